// Round 2
// baseline (146.097 us; speedup 1.0000x reference)
//
#include <hip/hip_runtime.h>
#include <stdint.h>
#include <stddef.h>

#define NROWS 8192
#define DIM   1024
#define RB    512      // fp4 bytes per row (DIM/2)
#define TEMP  10.0f

#define BM 256
#define BN 256
#define BK 128         // K elements per tile; 64 bytes fp4 per row
#define NT (DIM / BK)  // 8 K-tiles

typedef __attribute__((ext_vector_type(8))) int i32x8;
typedef __attribute__((ext_vector_type(16))) float floatx16;

// async 16B global->LDS (global_load_lds_dwordx4); LDS dest is wave-uniform
// base + lane*16 -- all staging dests are slot*16 by construction.
__device__ __forceinline__ void load16_lds(const unsigned char* g, unsigned char* l) {
    __builtin_amdgcn_global_load_lds(
        (__attribute__((address_space(1))) void*)(g),
        (__attribute__((address_space(3))) void*)(l),
        16, 0, 0);
}

// fp4 e2m1 quantize of x (already in grid units, sigma~1): nearest of
// {0,.5,1,1.5,2,3,4,6} with sign. 7-threshold chain, branch-free.
__device__ __forceinline__ unsigned fp4q(float x) {
    float a = fabsf(x);
    a = fminf(a, 6.0f);
    unsigned c = (unsigned)(a >= 0.25f) + (unsigned)(a >= 0.75f)
               + (unsigned)(a >= 1.25f) + (unsigned)(a >= 1.75f)
               + (unsigned)(a >= 2.5f)  + (unsigned)(a >= 3.5f)
               + (unsigned)(a >= 5.0f);
    return c | ((__float_as_uint(x) >> 28) & 8u);
}

// ---------------------------------------------------------------------------
// Quantized layout (per matrix, 4 MB) -- MFMA-fragment-linear:
//   element e of row r: chunk c = e>>5 (16B = 32 fp4), it = c>>2,
//   ks = (c>>1)&1, fh = c&1
//   byte = it*524288 + (r>>5)*2048 + ks*1024 + fh*512 + (r&31)*16
// => per (rowgroup, it, ks): 1 KB fragment, lane-linear (lane = fh*32 + fr,
//    16 B per lane). GEMM reads it with ZERO address swizzle: LDS frags are
//    ds_read_b128 at base+lane*16+imm (conflict-free), B frags are
//    global_load_dwordx4 of a contiguous 1 KB per wave (coalesced).
// ---------------------------------------------------------------------------

// Wave-per-row L2 normalize + quantize to fp4 e2m1 at fixed scale 2^-5
// (values x32 -> sigma ~1 grid unit). Fragment-linear stores via small LDS
// transpose bounce.
__global__ __launch_bounds__(256) void normalize_kernel(
    const float* __restrict__ img, const float* __restrict__ txt,
    unsigned char* __restrict__ imgq, unsigned char* __restrict__ txtq,
    float* __restrict__ out)
{
    __shared__ __align__(16) unsigned short sc[4][256];   // [wave][c*64+lane]
    const int t = threadIdx.x;
    const int lane = t & 63, wave = t >> 6;
    const int gw = blockIdx.x * 4 + wave;                 // row id, 0..16383
    const float* src = (gw < NROWS) ? img + (size_t)gw * DIM
                                    : txt + (size_t)(gw - NROWS) * DIM;
    float4 v[4];
    float ss = 0.f;
#pragma unroll
    for (int c = 0; c < 4; c++) {
        v[c] = ((const float4*)src)[lane + 64 * c];
        ss += v[c].x * v[c].x + v[c].y * v[c].y + v[c].z * v[c].z + v[c].w * v[c].w;
    }
#pragma unroll
    for (int off = 32; off; off >>= 1) ss += __shfl_xor(ss, off);
    const float scale = 32.0f / fmaxf(sqrtf(ss), 1e-12f);   // x32 = fp4 grid
#pragma unroll
    for (int c = 0; c < 4; c++) {
        unsigned p = fp4q(v[c].x * scale)
                   | (fp4q(v[c].y * scale) << 4)
                   | (fp4q(v[c].z * scale) << 8)
                   | (fp4q(v[c].w * scale) << 12);
        sc[wave][c * 64 + lane] = (unsigned short)p;   // ushort u covers elems [4u,4u+4)
    }
    __syncthreads();
    // 128 store units: (rr = row in block 0..3, k = chunk 0..31). Chunk k =
    // ushorts [8k..8k+8) of row rr. 4 consecutive t share (it,ks,fh) and write
    // 4 consecutive fr*16 slots -> 64B-line coalesced.
    if (t < 128) {
        const int rr = t & 3, k = t >> 2;
        const int gr0 = blockIdx.x * 4;      // block never straddles img/txt (4 | 8192)
        unsigned char* dq = (gr0 < NROWS) ? imgq : txtq;
        const int r = (gr0 < NROWS ? gr0 : gr0 - NROWS) + rr;
        const int4 d = *(const int4*)&sc[rr][k * 8];
        const int it = k >> 2, ks = (k >> 1) & 1, fh = k & 1;
        *(int4*)(dq + (size_t)it * 524288 + (size_t)((r >> 5) * 2048
                 + ks * 1024 + fh * 512 + (r & 31) * 16)) = d;
    }
    if (gw == 0 && lane == 0) out[0] = 0.f;   // zero the atomic target
}

// Persistent 256-block NT-GEMM on fp4 e2m1 via MX-scaled MFMA 32x32x64.
// Each block owns one 256-row A panel (RESIDENT in LDS, 128 KB, loaded once)
// and sweeps 4 output tiles n = n0+8k. B operands are fetched straight from
// global (L2-resident, 8 MB total) into registers -- NO B staging, NO vmcnt
// bookkeeping, and ZERO barriers in the 64-step main stream. Waves drift
// freely; the compiler software-pipelines the fully unrolled stream.
// Per step (= one ks of one K-tile): prefetch step s+1's operands
// (4 ds_read_b128 from resident A + 2 global_load_dwordx4 for B) into the
// alternate tuple set, then 8 MFMAs from the current set.
// Operand tuples are persistent zero-uppered i32x8 (cbsz/blgp=4 reads only
// regs 0..3); only the low int4 is overwritten -> no per-call zero movs.
__global__ __launch_bounds__(512, 2) void simloss_kernel(
    const unsigned char* __restrict__ An,   // img fp4, fragment-linear
    const unsigned char* __restrict__ Bn,   // txt fp4, fragment-linear
    const float* __restrict__ bias,
    float* __restrict__ out)
{
    __shared__ __align__(16) unsigned char As[8 * 16384];  // resident A panel
    __shared__ float red[4][8];

    const int t = threadIdx.x;
    const int lane = t & 63;
    const int wave = t >> 6;

    const int bid = blockIdx.x;        // 0..255
    const int blockM = bid >> 3;       // 0..31, fixed per block
    const int n0 = bid & 3 ? (bid & 7) : (bid & 7);  // 0..7 (XCD-correlated)

    // ---- prologue: DMA the whole A panel into LDS (16 loads/thread) ----
    {
        const unsigned char* gA = An + (size_t)blockM * 16384 + t * 16;
#pragma unroll
        for (int it = 0; it < 8; it++) {
#pragma unroll
            for (int j = 0; j < 2; j++)
                load16_lds(gA + (size_t)it * 524288 + j * 8192,
                           As + it * 16384 + j * 8192 + t * 16);
        }
    }
    asm volatile("s_waitcnt vmcnt(0)" ::: "memory");
    __syncthreads();                   // the ONLY structural barrier

    // wave tile: 2x4 waves, each 128x64 (mi 0..3, ni 0..1 of 32x32 tiles)
    const int waveM = (wave >> 2) * 128;
    const int waveN = (wave & 3) * 64;
    const int rgA = (wave >> 2) * 4;    // A rowgroup base (of 8)
    const int cgB = (wave & 3) * 2;     // B rowgroup base (of 8)
    const int fr = lane & 31;
    const int fh = lane >> 5;

    // persistent operand tuples, uppers zeroed once (HW reads regs 0..3 only)
    i32x8 aT[2][4], bT[2][2];
#pragma unroll
    for (int p = 0; p < 2; p++) {
#pragma unroll
        for (int mi = 0; mi < 4; mi++) aT[p][mi] = (i32x8)0;
#pragma unroll
        for (int ni = 0; ni < 2; ni++) bT[p][ni] = (i32x8)0;
    }

#define LOADA(P, IT, KS)                                                        \
    {                                                                           \
        _Pragma("unroll")                                                       \
        for (int mi_ = 0; mi_ < 4; mi_++)                                       \
            *(int4*)&aT[P][mi_] = *(const int4*)(As + (IT) * 16384              \
                + (rgA + mi_) * 2048 + (KS) * 1024 + lane * 16);                \
    }
#define LOADB(P, N, IT, KS)                                                     \
    {                                                                           \
        _Pragma("unroll")                                                       \
        for (int ni_ = 0; ni_ < 2; ni_++)                                       \
            *(int4*)&bT[P][ni_] = *(const int4*)(Bn + (size_t)(IT) * 524288     \
                + (size_t)(((N) * 8 + cgB + ni_) * 2048 + (KS) * 1024           \
                           + lane * 16));                                       \
    }

    // preload step 0 (tile k=0, it=0, ks=0) into set 0
    LOADA(0, 0, 0);
    LOADB(0, n0, 0, 0);

    const float bv = bias[0];
    const float c1 = -TEMP * 1.4426950408889634f / 1024.0f;  // on raw acc
    const float c0 = bv * 1.4426950408889634f;

#pragma unroll
    for (int k = 0; k < 4; k++) {
        const int n = n0 + 8 * k;
        floatx16 acc[4][2];
#pragma unroll
        for (int mi = 0; mi < 4; mi++)
#pragma unroll
            for (int ni = 0; ni < 2; ni++)
                acc[mi][ni] = (floatx16)(0.f);

#pragma unroll
        for (int ss = 0; ss < 16; ss++) {
            const int s = k * 16 + ss;
            const int p = s & 1;
            // prefetch step s+1 into the alternate set (always legal: A is
            // resident LDS, B is a pure global read -- no sync needed even
            // across output-tile boundaries)
            if (s < 63) {
                const int s1 = s + 1;
                const int it1 = (s1 >> 1) & 7;
                const int ks1 = s1 & 1;
                const int n1 = n0 + 8 * (s1 >> 4);
                LOADA(p ^ 1, it1, ks1);
                LOADB(p ^ 1, n1, it1, ks1);
            }
#pragma unroll
            for (int mi = 0; mi < 4; mi++)
#pragma unroll
                for (int ni = 0; ni < 2; ni++)
                    acc[mi][ni] = __builtin_amdgcn_mfma_scale_f32_32x32x64_f8f6f4(
                        aT[p][mi], bT[p][ni], acc[mi][ni],
                        4, 4,                 // cbsz=FP4(e2m1), blgp=FP4(e2m1)
                        0, 0x7f7f7f7f,        // opsel_a, scale_a = 2^0
                        0, 0x7f7f7f7f);       // opsel_b, scale_b = 2^0
        }

        // ---- epilogue for tile (blockM, n) -- numerics identical to r1 ----
        // Raw acc = 1024*sim. logit = -10*sim + b, x = label*logit.
        //   softplus(x) = (x+|x|)/2 + log(1+e^-|x|)
        //   sum(x)/2 = sum_diag(logit) - sum_all(logit)/2   (linear!)
        float accP = 0.f, accQ = 0.f, accD = 0.f;
        const int gi0 = blockM * BM + waveM + 4 * fh;
        const int gj0 = n * BN + waveN + fr;
#pragma unroll
        for (int mi = 0; mi < 4; mi++) {
#pragma unroll
            for (int ni = 0; ni < 2; ni++) {
#pragma unroll
                for (int reg = 0; reg < 16; reg++) {
                    float sv = acc[mi][ni][reg];          // raw = 1024*sim
                    float w = fmaf(sv, c1, c0);
                    float e2 = __builtin_amdgcn_exp2f(-fabsf(w));
                    accP += __builtin_amdgcn_logf(1.0f + e2);   // v_log = log2
                    accP = fmaf(0.5f, fabsf(w), accP);
                    accQ += sv;
                }
            }
        }
        const bool diagblk = (n == blockM);
        if (diagblk) {
#pragma unroll
            for (int mi = 0; mi < 4; mi++)
#pragma unroll
                for (int ni = 0; ni < 2; ni++)
#pragma unroll
                    for (int reg = 0; reg < 16; reg++) {
                        int ig = gi0 + mi * 32 + (reg & 3) + 8 * (reg >> 2);
                        int jg = gj0 + ni * 32;
                        if (ig == jg) accD += acc[mi][ni][reg];
                    }
        }
#pragma unroll
        for (int off = 32; off; off >>= 1) {
            accP += __shfl_xor(accP, off);
            accQ += __shfl_xor(accQ, off);
            accD += __shfl_xor(accD, off);
        }
        // per-wave combined contribution (all linear):
        //   ln2*P + 5*(Qraw/1024) - 10*(Draw/1024)
        if (lane == 0) {
            float wcon = fmaf(0.6931471805599453f, accP,
                              fmaf(5.0f / 1024.0f, accQ,
                                   diagblk ? (-TEMP / 1024.0f) * accD : 0.f));
            red[k][wave] = wcon;
        }
        __syncthreads();
        if (t == 0) {
            float sum = 0.f;
#pragma unroll
            for (int w = 0; w < 8; w++) sum += red[k][w];
            sum += -32768.0f * bv;
            if (diagblk) sum += 256.0f * bv;
            atomicAdd(out, sum * (1.0f / 8192.0f));
        }
    }
#undef LOADA
#undef LOADB
}

extern "C" void kernel_launch(void* const* d_in, const int* in_sizes, int n_in,
                              void* d_out, int out_size, void* d_ws, size_t ws_size,
                              hipStream_t stream) {
    const float* txt = (const float*)d_in[0];   // text_embeddings [8192][1024]
    const float* img = (const float*)d_in[1];   // image_embeddings [8192][1024]
    const float* bias = (const float*)d_in[2];  // [1]
    float* out = (float*)d_out;

    unsigned char* imgq = (unsigned char*)d_ws;                      // 4 MB fp4
    unsigned char* txtq = imgq + (size_t)NROWS * RB;                 // 4 MB fp4

    normalize_kernel<<<dim3(2 * NROWS / 4), dim3(256), 0, stream>>>(
        img, txt, imgq, txtq, out);

    simloss_kernel<<<dim3(256), dim3(512), 0, stream>>>(
        imgq, txtq, bias, out);
}